// Round 7
// baseline (410.903 us; speedup 1.0000x reference)
//
#include <hip/hip_runtime.h>
#include <stdint.h>

// ---------------------------------------------------------------------------
// GNNWithMoE: 2x GGNN(edge-embed + gather + GRU) -> soft MoE -> mean pool
// ALL float tensors fp32; ints int32; out fp32. GEMMs via bf16 MFMA.
//
// Round-7: k_bucket write amplification fix. Round-6 showed 51MB WRITE_SIZE
// (= 800k scattered 8B writes x 64B lines, ping-ponged across 8 XCDs).
// Buckets are now partitioned into 8 sub-buckets of 8 entries keyed by
// blockIdx&7 (~XCD id under round-robin dispatch): each 64B sub-bucket line
// and its counters are written by one XCD only. Per-(node,sub) count is
// ~Poisson(2); P(>8)~2.4e-4 -> ~95 overflow edges handled by k_ovf
// (correct for any input).
// Workspace (16B-aligned):
//   m[N*64] f32 | h[N*64] f32 | bkt[N*64] int2 | cur[N*8] i32 |
//   ovfcnt[4] i32 | ovf[32768] i32 | wbf[65792] bf16 | partial[B*PS*64] f32
// ---------------------------------------------------------------------------

#define SUBCAP 8
#define OVF_MAX 32768
#define PS 16   // pool splits per graph

typedef __bf16 bf16x8 __attribute__((ext_vector_type(8)));
typedef float floatx4 __attribute__((ext_vector_type(4)));
typedef unsigned short us8 __attribute__((ext_vector_type(8)));

__device__ __forceinline__ unsigned short f2bf(float f){
  union { float f; unsigned u; } c; c.f = f;
  unsigned r = c.u + 0x7FFFu + ((c.u >> 16) & 1u);
  return (unsigned short)(r >> 16);
}
__device__ __forceinline__ float sigm(float x){ return 1.f/(1.f + __expf(-x)); }

// fused: weight fp32->bf16 conversion + zero cur/ovfcnt  (cur is N*8 now)
__global__ void k_init(const float* __restrict__ s0, const float* __restrict__ s1,
                       const float* __restrict__ s2, const float* __restrict__ s3,
                       const float* __restrict__ s4, const float* __restrict__ s5,
                       unsigned short* __restrict__ dst,
                       int* __restrict__ cur, int* __restrict__ ovfcnt, int N8){
  int i = blockIdx.x*blockDim.x + threadIdx.x;
  if (i < N8) cur[i] = 0;
  if (i == 0){ ovfcnt[0] = 0; }
  if (i >= 65792) return;
  const float* s; int off;
  if      (i < 12288){ s = s0; off = i; }
  else if (i < 24576){ s = s1; off = i - 12288; }
  else if (i < 36864){ s = s2; off = i - 24576; }
  else if (i < 49152){ s = s3; off = i - 36864; }
  else if (i < 49408){ s = s4; off = i - 49152; }
  else               { s = s5; off = i - 49408; }
  dst[i] = f2bf(s[off]);
}

// one atomic per edge into an XCD-local sub-bucket; overflow -> list
__global__ void k_bucket(const int* __restrict__ ei,
                         int* __restrict__ cur, int2* __restrict__ bkt,
                         int* __restrict__ ovfcnt, int* __restrict__ ovf, int E){
  int e = blockIdx.x*blockDim.x + threadIdx.x;
  if (e >= E) return;
  int sub = blockIdx.x & 7;          // ~XCD id under round-robin dispatch
  int s = ei[e];
  int d = ei[E + e];
  int pos = atomicAdd(&cur[d*8 + sub], 1);
  if (pos < SUBCAP){
    bkt[(size_t)d*64 + sub*SUBCAP + pos] = make_int2(s, e);
  } else {
    int o = atomicAdd(ovfcnt, 1);
    if (o < OVF_MAX) ovf[o] = e;
  }
}

// one wave per node, lane=dim; lane d also owns bucket slot (sub=d>>3,k=d&7):
// m[n,d] = x[n,d] + (deg+1)*b_edge[d] + w_edge[d,:].sum_e(ea[e,:]) + sum_e x[src,d]
// (overflow edges' x/ea terms added later by k_ovf; their bias IS counted here)
__global__ void __launch_bounds__(256) k_gather(
    const int* __restrict__ cur, const int2* __restrict__ bkt,
    const float* __restrict__ ea,
    const float* __restrict__ xin,
    const float* __restrict__ w_edge, const float* __restrict__ b_edge,
    float* __restrict__ m, int N){
  int n = (int)(((long long)blockIdx.x*blockDim.x + threadIdx.x) >> 6);
  if (n >= N) return;
  int d = threadIdx.x & 63;
  const int4* cp = (const int4*)(cur + (size_t)n*8);
  int4 c0 = cp[0], c1 = cp[1];
  int cnt0 = c0.x, cnt1 = c0.y, cnt2 = c0.z, cnt3 = c0.w;
  int cnt4 = c1.x, cnt5 = c1.y, cnt6 = c1.z, cnt7 = c1.w;
  int degAll = cnt0+cnt1+cnt2+cnt3+cnt4+cnt5+cnt6+cnt7;
  int cc[8];
  cc[0]=min(cnt0,SUBCAP); cc[1]=min(cnt1,SUBCAP); cc[2]=min(cnt2,SUBCAP); cc[3]=min(cnt3,SUBCAP);
  cc[4]=min(cnt4,SUBCAP); cc[5]=min(cnt5,SUBCAP); cc[6]=min(cnt6,SUBCAP); cc[7]=min(cnt7,SUBCAP);

  float4 wv = *(const float4*)(w_edge + d*4);
  float acc = xin[(size_t)n*64 + d] + (float)(degAll + 1) * b_edge[d];
  float esx = 0.f, esy = 0.f, esz = 0.f, esw = 0.f;

  int2 se = make_int2(0, -1);
  if ((d & 7) < cc[d >> 3]) se = bkt[(size_t)n*64 + d];   // coalesced 512B wave-load
  if (se.y >= 0){
    float4 v = *(const float4*)(ea + (size_t)se.y*4);
    esx = v.x; esy = v.y; esz = v.z; esw = v.w;
  }
  // x-row gather: iterate valid slots (counts are wave-uniform)
#pragma unroll
  for (int j = 0; j < 8; ++j){
    int cj = cc[j];
    for (int k = 0; k < cj; ++k){
      int s = __shfl(se.x, j*SUBCAP + k);
      acc += xin[(size_t)s*64 + d];
    }
  }
  // butterfly-sum ea over all 64 lanes (invalid lanes contribute 0)
#pragma unroll
  for (int off = 1; off < 64; off <<= 1){
    esx += __shfl_xor(esx, off);
    esy += __shfl_xor(esy, off);
    esz += __shfl_xor(esz, off);
    esw += __shfl_xor(esw, off);
  }
  acc += esx*wv.x + esy*wv.y + esz*wv.z + esw*wv.w;
  m[(size_t)n*64 + d] = acc;
}

// fallback for sub-bucket-overflow edges (~1e2 expected): atomic scatter, no bias
__global__ void k_ovf(const int* __restrict__ ei, const float* __restrict__ ea,
                      const float* __restrict__ xin, const float* __restrict__ w_edge,
                      const int* __restrict__ ovf, const int* __restrict__ ovfcnt,
                      float* __restrict__ m, int E){
  int cnt = *ovfcnt; if (cnt > OVF_MAX) cnt = OVF_MAX;
  int nwaves = (gridDim.x * blockDim.x) >> 6;
  int wid = (int)((blockIdx.x*blockDim.x + threadIdx.x) >> 6);
  int d = threadIdx.x & 63;
  for (int k = wid; k < cnt; k += nwaves){
    int e = ovf[k];
    int s = ei[e], dst = ei[E + e];
    float4 v  = *(const float4*)(ea + (size_t)e*4);
    float4 wv = *(const float4*)(w_edge + d*4);
    float msg = xin[(size_t)s*64 + d] + v.x*wv.x + v.y*wv.y + v.z*wv.z + v.w*wv.w;
    atomicAdd(&m[(size_t)dst*64 + d], msg);
  }
}

// GRU cell via MFMA: gi = m @ w_ih^T, gh = x @ w_hh^T, one wave per 16 nodes.
// A layout: A[m=lane&15][k=quad*8+j]; C/D: col=lane&15, row=quad*4+reg (m89/m91).
__global__ void __launch_bounds__(256) k_gru(
    const float* __restrict__ m, const float* x,
    const unsigned short* __restrict__ wih, const unsigned short* __restrict__ whh,
    const float* __restrict__ b_ih, const float* __restrict__ b_hh,
    float* out, int tiles, int N){
  int wid = (int)(((long long)blockIdx.x*blockDim.x + threadIdx.x) >> 6);
  if (wid >= tiles) return;
  int lane = threadIdx.x & 63;
  int col = lane & 15, quad = lane >> 4;
  int na = wid*16 + col; if (na > N-1) na = N-1;

  bf16x8 am[2], ax[2];
#pragma unroll
  for (int ks = 0; ks < 2; ++ks){
    int kb = ks*32 + quad*8;
    const float4* mp = (const float4*)(m + (size_t)na*64 + kb);
    float4 lo = mp[0], hi = mp[1];
    us8 tm;
    tm[0]=f2bf(lo.x); tm[1]=f2bf(lo.y); tm[2]=f2bf(lo.z); tm[3]=f2bf(lo.w);
    tm[4]=f2bf(hi.x); tm[5]=f2bf(hi.y); tm[6]=f2bf(hi.z); tm[7]=f2bf(hi.w);
    am[ks] = __builtin_bit_cast(bf16x8, tm);
    const float4* xp = (const float4*)(x + (size_t)na*64 + kb);
    float4 xlo = xp[0], xhi = xp[1];
    us8 tx;
    tx[0]=f2bf(xlo.x); tx[1]=f2bf(xlo.y); tx[2]=f2bf(xlo.z); tx[3]=f2bf(xlo.w);
    tx[4]=f2bf(xhi.x); tx[5]=f2bf(xhi.y); tx[6]=f2bf(xhi.z); tx[7]=f2bf(xhi.w);
    ax[ks] = __builtin_bit_cast(bf16x8, tx);
  }

  floatx4 ai[12], ah[12];
#pragma unroll
  for (int nt = 0; nt < 12; ++nt){ ai[nt] = (floatx4)0.f; ah[nt] = (floatx4)0.f; }
#pragma unroll
  for (int nt = 0; nt < 12; ++nt){
    int r = nt*16 + col;   // output row of w (0..191)
#pragma unroll
    for (int ks = 0; ks < 2; ++ks){
      int kb = ks*32 + quad*8;
      bf16x8 bi = __builtin_bit_cast(bf16x8, *(const us8*)(wih + (size_t)r*64 + kb));
      ai[nt] = __builtin_amdgcn_mfma_f32_16x16x32_bf16(am[ks], bi, ai[nt], 0,0,0);
      bf16x8 bh = __builtin_bit_cast(bf16x8, *(const us8*)(whh + (size_t)r*64 + kb));
      ah[nt] = __builtin_amdgcn_mfma_f32_16x16x32_bf16(ax[ks], bh, ah[nt], 0,0,0);
    }
  }

#pragma unroll
  for (int nt = 0; nt < 4; ++nt){
    int d = nt*16 + col;
    float bir = b_ih[d],      bhr = b_hh[d];
    float biz = b_ih[64+d],   bhz = b_hh[64+d];
    float bin = b_ih[128+d],  bhn = b_hh[128+d];
#pragma unroll
    for (int rg = 0; rg < 4; ++rg){
      int node = wid*16 + quad*4 + rg;
      if (node >= N) continue;
      float rr = sigm(ai[nt  ][rg] + bir + ah[nt  ][rg] + bhr);
      float zz = sigm(ai[nt+4][rg] + biz + ah[nt+4][rg] + bhz);
      float nn = tanhf(ai[nt+8][rg] + bin + rr*(ah[nt+8][rg] + bhn));
      float xv = x[(size_t)node*64 + d];
      float hv = (1.f - zz)*nn + zz*xv;
      out[(size_t)node*64 + d] = fmaxf(hv, 0.f);
    }
  }
}

// MoE: gate logits + 4 experts via MFMA, softmax combine -> v[node][64] stores.
__global__ void __launch_bounds__(256) k_moe(
    const float* __restrict__ h,
    const unsigned short* __restrict__ gate_w, const float* __restrict__ gate_b,
    const unsigned short* __restrict__ exp_w,  const float* __restrict__ exp_b,
    float* __restrict__ v_out, int tiles, int N){
  __shared__ float gsm[4][16][4];
  int gwid = (int)(((long long)blockIdx.x*blockDim.x + threadIdx.x) >> 6);
  int w = threadIdx.x >> 6;
  int lane = threadIdx.x & 63;
  int col = lane & 15, quad = lane >> 4;
  bool active = gwid < tiles;

  floatx4 accg = (floatx4)0.f;
  floatx4 acce[4][4];
#pragma unroll
  for (int e=0;e<4;++e)
#pragma unroll
    for (int nt=0;nt<4;++nt) acce[e][nt] = (floatx4)0.f;

  if (active){
    int na = gwid*16 + col; if (na > N-1) na = N-1;
    bf16x8 a[2];
#pragma unroll
    for (int ks=0; ks<2; ++ks){
      int kb = ks*32 + quad*8;
      const float4* hp = (const float4*)(h + (size_t)na*64 + kb);
      float4 lo = hp[0], hi = hp[1];
      us8 th;
      th[0]=f2bf(lo.x); th[1]=f2bf(lo.y); th[2]=f2bf(lo.z); th[3]=f2bf(lo.w);
      th[4]=f2bf(hi.x); th[5]=f2bf(hi.y); th[6]=f2bf(hi.z); th[7]=f2bf(hi.w);
      a[ks] = __builtin_bit_cast(bf16x8, th);
      us8 braw = {0,0,0,0,0,0,0,0};
      if (col < 4) braw = *(const us8*)(gate_w + col*64 + kb);
      accg = __builtin_amdgcn_mfma_f32_16x16x32_bf16(a[ks], __builtin_bit_cast(bf16x8, braw), accg, 0,0,0);
    }
#pragma unroll
    for (int e=0;e<4;++e)
#pragma unroll
      for (int nt=0;nt<4;++nt)
#pragma unroll
        for (int ks=0;ks<2;++ks){
          int kb = ks*32 + quad*8;
          bf16x8 b = __builtin_bit_cast(bf16x8,
              *(const us8*)(exp_w + ((size_t)e*64 + nt*16 + col)*64 + kb));
          acce[e][nt] = __builtin_amdgcn_mfma_f32_16x16x32_bf16(a[ks], b, acce[e][nt], 0,0,0);
        }
    if (col < 4){
      float gb = gate_b[col];
#pragma unroll
      for (int rg=0;rg<4;++rg) gsm[w][quad*4+rg][col] = accg[rg] + gb;
    }
  }
  __syncthreads();
  if (!active) return;

#pragma unroll
  for (int rg=0; rg<4; ++rg){
    int nrow = quad*4 + rg;
    int node = gwid*16 + nrow;
    if (node >= N) continue;
    float g0=gsm[w][nrow][0], g1=gsm[w][nrow][1], g2=gsm[w][nrow][2], g3=gsm[w][nrow][3];
    float mx = fmaxf(fmaxf(g0,g1), fmaxf(g2,g3));
    float e0=__expf(g0-mx), e1=__expf(g1-mx), e2=__expf(g2-mx), e3=__expf(g3-mx);
    float inv = 1.f/(e0+e1+e2+e3);
    float w0=e0*inv, w1=e1*inv, w2=e2*inv, w3=e3*inv;
#pragma unroll
    for (int nt=0;nt<4;++nt){
      int o = nt*16 + col;
      float v = w0*fmaxf(acce[0][nt][rg] + exp_b[      o], 0.f)
              + w1*fmaxf(acce[1][nt][rg] + exp_b[ 64 + o], 0.f)
              + w2*fmaxf(acce[2][nt][rg] + exp_b[128 + o], 0.f)
              + w3*fmaxf(acce[3][nt][rg] + exp_b[192 + o], 0.f);
      v_out[(size_t)node*64 + o] = v;
    }
  }
}

__device__ __forceinline__ int lower_bound_i(const int* __restrict__ a, int n, int key){
  int lo = 0, hi = n;
  while (lo < hi){ int mid = (lo + hi) >> 1; if (a[mid] < key) lo = mid + 1; else hi = mid; }
  return lo;
}

// stage 1: B*PS blocks; block (g,s) reduces 1/PS of graph g's nodes.
__global__ void __launch_bounds__(256) k_pool(
    const float* __restrict__ v, const int* __restrict__ batch, int N,
    float* __restrict__ partial){
  __shared__ float red[4][64];
  int g = blockIdx.x / PS, s = blockIdx.x % PS;
  int t = threadIdx.x, d = t & 63, r = t >> 6;
  int start = lower_bound_i(batch, N, g);
  int end   = lower_bound_i(batch, N, g + 1);
  int len = end - start;
  int per = (len + PS - 1) / PS;
  int s0 = start + s*per;
  int s1 = s0 + per; if (s1 > end) s1 = end;
  float acc = 0.f;
  for (int i = s0 + r; i < s1; i += 4)
    acc += v[(size_t)i*64 + d];
  red[r][d] = acc;
  __syncthreads();
  if (r == 0)
    partial[(size_t)blockIdx.x*64 + d] = red[0][d] + red[1][d] + red[2][d] + red[3][d];
}

// stage 2: B blocks; sum PS partials, mean, write emb twice + logits head.
__global__ void __launch_bounds__(64) k_head(
    const float* __restrict__ partial, const int* __restrict__ batch, int N, int B,
    const float* __restrict__ ldxb,
    const float* __restrict__ proj_w, const float* __restrict__ proj_b,
    const float* __restrict__ fc_w, const float* __restrict__ fc_b,
    float* __restrict__ out){
  __shared__ float ges[64];
  int b = blockIdx.x, d = threadIdx.x;
  int start = lower_bound_i(batch, N, b);
  int end   = lower_bound_i(batch, N, b + 1);
  float sum = 0.f;
#pragma unroll
  for (int s = 0; s < PS; ++s)
    sum += partial[((size_t)b*PS + s)*64 + d];
  float ge = sum / fmaxf((float)(end - start), 1.f);
  ges[d] = ge;
  out[(size_t)b*64 + d]                = ge;
  out[(size_t)B*64 + (size_t)b*64 + d] = ge;
  __syncthreads();
  if (d < 10){
    float acc = fc_b[d];
    float fl = ldxb[b];
    const float* fr = fc_w + d*164;
    for (int p = 0; p < 100; ++p) acc += (fl*proj_w[p] + proj_b[p]) * fr[p];
    for (int dd = 0; dd < 64; ++dd) acc += ges[dd]*fr[100 + dd];
    out[(size_t)B*128 + (size_t)b*10 + d] = acc;
  }
}

extern "C" void kernel_launch(void* const* d_in, const int* in_sizes, int n_in,
                              void* d_out, int out_size, void* d_ws, size_t ws_size,
                              hipStream_t stream){
  const float* x      = (const float*)d_in[0];
  const int*   ei     = (const int*)d_in[1];
  const float* ea     = (const float*)d_in[2];
  const int*   batch  = (const int*)d_in[3];
  const float* ldxb   = (const float*)d_in[4];
  const float* w_edge1= (const float*)d_in[5];
  const float* b_edge1= (const float*)d_in[6];
  const float* w_ih1  = (const float*)d_in[7];
  const float* w_hh1  = (const float*)d_in[8];
  const float* b_ih1  = (const float*)d_in[9];
  const float* b_hh1  = (const float*)d_in[10];
  const float* w_edge2= (const float*)d_in[11];
  const float* b_edge2= (const float*)d_in[12];
  const float* w_ih2  = (const float*)d_in[13];
  const float* w_hh2  = (const float*)d_in[14];
  const float* b_ih2  = (const float*)d_in[15];
  const float* b_hh2  = (const float*)d_in[16];
  const float* gate_w = (const float*)d_in[17];
  const float* gate_b = (const float*)d_in[18];
  const float* exp_w  = (const float*)d_in[19];
  const float* exp_b  = (const float*)d_in[20];
  const float* proj_w = (const float*)d_in[21];
  const float* proj_b = (const float*)d_in[22];
  const float* fc_w   = (const float*)d_in[23];
  const float* fc_b   = (const float*)d_in[24];
  float* out = (float*)d_out;

  int N = in_sizes[0] / 64;
  int E = in_sizes[1] / 2;
  int B = in_sizes[4];
  int tiles = (N + 15) / 16;
  int nTot = N * 64;

  // workspace layout (all segment sizes multiples of 16B)
  float* m      = (float*)d_ws;                    // N*64 f32 (also MoE v)
  float* h      = m + (size_t)nTot;                // N*64 f32
  int2*  bkt    = (int2*)(h + (size_t)nTot);       // N*64 int2 (8 subs x 8)
  int*   cur    = (int*)(bkt + (size_t)N*64);      // N*8 i32
  int*   ovfcnt = cur + (size_t)N*8;               // 4 i32 (padded)
  int*   ovf    = ovfcnt + 4;                      // OVF_MAX i32
  unsigned short* wbf = (unsigned short*)(ovf + OVF_MAX); // 65792 bf16
  float* partial = (float*)(wbf + 65792);          // B*PS*64 f32
  unsigned short* wih1bf = wbf;
  unsigned short* whh1bf = wbf + 12288;
  unsigned short* wih2bf = wbf + 24576;
  unsigned short* whh2bf = wbf + 36864;
  unsigned short* gatebf = wbf + 49152;
  unsigned short* expbf  = wbf + 49408;

  dim3 blk(256);
  int edgeBlocks = (E + 255)/256;
  int nodeWaveBlocks = (N + 3)/4;       // one wave per node
  int waveBlocks = (tiles + 3)/4;       // one wave per 16-node tile
  int N8 = N*8;
  int initBlocks = ((N8 > 65792 ? N8 : 65792) + 255)/256;

  k_init<<<initBlocks, blk, 0, stream>>>(w_ih1, w_hh1, w_ih2, w_hh2, gate_w, exp_w,
                                         wbf, cur, ovfcnt, N8);
  k_bucket<<<edgeBlocks, blk, 0, stream>>>(ei, cur, bkt, ovfcnt, ovf, E);
  // ---- layer 1 ----
  k_gather<<<nodeWaveBlocks, blk, 0, stream>>>(cur, bkt, ea, x, w_edge1, b_edge1, m, N);
  k_ovf<<<8, blk, 0, stream>>>(ei, ea, x, w_edge1, ovf, ovfcnt, m, E);
  k_gru<<<waveBlocks, blk, 0, stream>>>(m, x, wih1bf, whh1bf, b_ih1, b_hh1, h, tiles, N);
  // ---- layer 2 (in-place h update; wave/lane-exclusive, safe) ----
  k_gather<<<nodeWaveBlocks, blk, 0, stream>>>(cur, bkt, ea, h, w_edge2, b_edge2, m, N);
  k_ovf<<<8, blk, 0, stream>>>(ei, ea, h, w_edge2, ovf, ovfcnt, m, E);
  k_gru<<<waveBlocks, blk, 0, stream>>>(m, h, wih2bf, whh2bf, b_ih2, b_hh2, h, tiles, N);
  // ---- MoE -> v (reuse m), two-stage segmented-mean pool + heads ----
  k_moe<<<waveBlocks, blk, 0, stream>>>(h, gatebf, gate_b, expbf, exp_b, m, tiles, N);
  k_pool<<<B*PS, blk, 0, stream>>>(m, batch, N, partial);
  k_head<<<B, 64, 0, stream>>>(partial, batch, N, B, ldxb, proj_w, proj_b, fc_w, fc_b, out);
}

// Round 8
// 365.600 us; speedup vs baseline: 1.1239x; 1.1239x over previous
//
#include <hip/hip_runtime.h>
#include <stdint.h>

// ---------------------------------------------------------------------------
// GNNWithMoE: 2x GGNN(edge-embed + gather + GRU) -> soft MoE -> mean pool
// ALL float tensors fp32; ints int32; out fp32. GEMMs via bf16 MFMA.
//
// Round-8 gather-path fix (round-7 post-mortem):
//  * cur[sub*N+n]: counter lines are XCD-local (round-7's cur[n*8+sub] left
//    the HOT atomics ping-ponging across all 8 XCDs).
//  * bkt stores ea as bf16x4 payload (written coalesced-read in k_bucket):
//    k_gather's 800k random ea line-fetches eliminated.
//  * gather x-loop: ballot mask + ctz lane-extract, 4 independent loads/iter
//    (round-7's 8 dynamic sub-loops destroyed ILP).
// Sub-bucket cap 8, ~Poisson(2) load; overflow -> k_ovf fallback (any input).
// Workspace (16B-aligned):
//   m[N*64] f32 | h[N*64] f32 | bkt_src[N*64] i32 | bkt_ea[N*64] ushort4 |
//   cur[8*N] i32 | ovfcnt[4] | ovf[32768] | wbf[65792] bf16 | partial[B*PS*64]
// ---------------------------------------------------------------------------

#define SUBCAP 8
#define OVF_MAX 32768
#define PS 16   // pool splits per graph

typedef __bf16 bf16x8 __attribute__((ext_vector_type(8)));
typedef float floatx4 __attribute__((ext_vector_type(4)));
typedef unsigned short us8 __attribute__((ext_vector_type(8)));

__device__ __forceinline__ unsigned short f2bf(float f){
  union { float f; unsigned u; } c; c.f = f;
  unsigned r = c.u + 0x7FFFu + ((c.u >> 16) & 1u);
  return (unsigned short)(r >> 16);
}
__device__ __forceinline__ float bf2f(unsigned short u){
  union { unsigned u; float f; } c; c.u = ((unsigned)u) << 16; return c.f;
}
__device__ __forceinline__ float sigm(float x){ return 1.f/(1.f + __expf(-x)); }

// fused: weight fp32->bf16 conversion + zero cur/ovfcnt  (cur is 8*N)
__global__ void k_init(const float* __restrict__ s0, const float* __restrict__ s1,
                       const float* __restrict__ s2, const float* __restrict__ s3,
                       const float* __restrict__ s4, const float* __restrict__ s5,
                       unsigned short* __restrict__ dst,
                       int* __restrict__ cur, int* __restrict__ ovfcnt, int N8){
  int i = blockIdx.x*blockDim.x + threadIdx.x;
  if (i < N8) cur[i] = 0;
  if (i == 0){ ovfcnt[0] = 0; }
  if (i >= 65792) return;
  const float* s; int off;
  if      (i < 12288){ s = s0; off = i; }
  else if (i < 24576){ s = s1; off = i - 12288; }
  else if (i < 36864){ s = s2; off = i - 24576; }
  else if (i < 49152){ s = s3; off = i - 36864; }
  else if (i < 49408){ s = s4; off = i - 49152; }
  else               { s = s5; off = i - 49408; }
  dst[i] = f2bf(s[off]);
}

// one atomic per edge into an XCD-local sub-bucket (counter AND data lines
// owned by one XCD under round-robin block dispatch); ea payload stored bf16.
__global__ void k_bucket(const int* __restrict__ ei, const float* __restrict__ ea,
                         int* __restrict__ cur, int* __restrict__ bkt_src,
                         ushort4* __restrict__ bkt_ea,
                         int* __restrict__ ovfcnt, int* __restrict__ ovf,
                         int E, int N){
  int e = blockIdx.x*blockDim.x + threadIdx.x;
  if (e >= E) return;
  int sub = blockIdx.x & 7;          // ~XCD id under round-robin dispatch
  int s = ei[e];
  int d = ei[E + e];
  size_t sb = (size_t)sub*N + d;
  int pos = atomicAdd(&cur[sb], 1);
  if (pos < SUBCAP){
    float4 v = *(const float4*)(ea + (size_t)e*4);
    ushort4 p; p.x = f2bf(v.x); p.y = f2bf(v.y); p.z = f2bf(v.z); p.w = f2bf(v.w);
    bkt_src[sb*SUBCAP + pos] = s;
    bkt_ea [sb*SUBCAP + pos] = p;
  } else {
    int o = atomicAdd(ovfcnt, 1);
    if (o < OVF_MAX) ovf[o] = e;
  }
}

// one wave per node, lane=dim; lane d also owns bucket slot (sub=d>>3,k=d&7):
// m[n,d] = x[n,d] + (deg+1)*b_edge[d] + w_edge[d,:].sum_e(ea[e,:]) + sum_e x[src,d]
// (overflow edges' x/ea terms added later by k_ovf; their bias IS counted here)
__global__ void __launch_bounds__(256) k_gather(
    const int* __restrict__ cur, const int* __restrict__ bkt_src,
    const ushort4* __restrict__ bkt_ea,
    const float* __restrict__ xin,
    const float* __restrict__ w_edge, const float* __restrict__ b_edge,
    float* __restrict__ m, int N){
  int n = (int)(((long long)blockIdx.x*blockDim.x + threadIdx.x) >> 6);
  if (n >= N) return;
  int d = threadIdx.x & 63;
  int sub = d >> 3, k = d & 7;
  size_t sb = (size_t)sub*N + n;
  int myc = cur[sb];
  // degAll = sum of the 8 sub-counts (each lane group replicates its sub's count)
  int contrib = (k == 0) ? myc : 0;
#pragma unroll
  for (int off = 1; off < 64; off <<= 1) contrib += __shfl_xor(contrib, off);
  int degAll = contrib;

  bool valid = k < min(myc, SUBCAP);
  int src = 0;
  float esx = 0.f, esy = 0.f, esz = 0.f, esw = 0.f;
  if (valid){
    src = bkt_src[sb*SUBCAP + k];
    ushort4 p = bkt_ea[sb*SUBCAP + k];
    esx = bf2f(p.x); esy = bf2f(p.y); esz = bf2f(p.z); esw = bf2f(p.w);
  }

  float4 wv = *(const float4*)(w_edge + d*4);
  float acc = xin[(size_t)n*64 + d] + (float)(degAll + 1) * b_edge[d];

  // x-row gather: wave-uniform ballot mask, ctz lane-extract, 4 loads in flight
  unsigned long long mm = __ballot(valid);
  while (mm){
    int l0 = (int)__builtin_ctzll(mm); mm &= mm - 1;
    int s0 = __shfl(src, l0);
    float a0 = xin[(size_t)s0*64 + d];
    float a1 = 0.f, a2 = 0.f, a3 = 0.f;
    if (mm){
      int l1 = (int)__builtin_ctzll(mm); mm &= mm - 1;
      int s1 = __shfl(src, l1);
      a1 = xin[(size_t)s1*64 + d];
      if (mm){
        int l2 = (int)__builtin_ctzll(mm); mm &= mm - 1;
        int s2 = __shfl(src, l2);
        a2 = xin[(size_t)s2*64 + d];
        if (mm){
          int l3 = (int)__builtin_ctzll(mm); mm &= mm - 1;
          int s3 = __shfl(src, l3);
          a3 = xin[(size_t)s3*64 + d];
        }
      }
    }
    acc += (a0 + a1) + (a2 + a3);
  }

  // butterfly-sum ea over all 64 lanes (invalid lanes contribute 0)
#pragma unroll
  for (int off = 1; off < 64; off <<= 1){
    esx += __shfl_xor(esx, off);
    esy += __shfl_xor(esy, off);
    esz += __shfl_xor(esz, off);
    esw += __shfl_xor(esw, off);
  }
  acc += esx*wv.x + esy*wv.y + esz*wv.z + esw*wv.w;
  m[(size_t)n*64 + d] = acc;
}

// fallback for sub-bucket-overflow edges (~1e2 expected): atomic scatter, no bias
__global__ void k_ovf(const int* __restrict__ ei, const float* __restrict__ ea,
                      const float* __restrict__ xin, const float* __restrict__ w_edge,
                      const int* __restrict__ ovf, const int* __restrict__ ovfcnt,
                      float* __restrict__ m, int E){
  int cnt = *ovfcnt; if (cnt > OVF_MAX) cnt = OVF_MAX;
  int nwaves = (gridDim.x * blockDim.x) >> 6;
  int wid = (int)((blockIdx.x*blockDim.x + threadIdx.x) >> 6);
  int d = threadIdx.x & 63;
  for (int k = wid; k < cnt; k += nwaves){
    int e = ovf[k];
    int s = ei[e], dst = ei[E + e];
    float4 v  = *(const float4*)(ea + (size_t)e*4);
    float4 wv = *(const float4*)(w_edge + d*4);
    float msg = xin[(size_t)s*64 + d] + v.x*wv.x + v.y*wv.y + v.z*wv.z + v.w*wv.w;
    atomicAdd(&m[(size_t)dst*64 + d], msg);
  }
}

// GRU cell via MFMA: gi = m @ w_ih^T, gh = x @ w_hh^T, one wave per 16 nodes.
// A layout: A[m=lane&15][k=quad*8+j]; C/D: col=lane&15, row=quad*4+reg (m89/m91).
__global__ void __launch_bounds__(256) k_gru(
    const float* __restrict__ m, const float* x,
    const unsigned short* __restrict__ wih, const unsigned short* __restrict__ whh,
    const float* __restrict__ b_ih, const float* __restrict__ b_hh,
    float* out, int tiles, int N){
  int wid = (int)(((long long)blockIdx.x*blockDim.x + threadIdx.x) >> 6);
  if (wid >= tiles) return;
  int lane = threadIdx.x & 63;
  int col = lane & 15, quad = lane >> 4;
  int na = wid*16 + col; if (na > N-1) na = N-1;

  bf16x8 am[2], ax[2];
#pragma unroll
  for (int ks = 0; ks < 2; ++ks){
    int kb = ks*32 + quad*8;
    const float4* mp = (const float4*)(m + (size_t)na*64 + kb);
    float4 lo = mp[0], hi = mp[1];
    us8 tm;
    tm[0]=f2bf(lo.x); tm[1]=f2bf(lo.y); tm[2]=f2bf(lo.z); tm[3]=f2bf(lo.w);
    tm[4]=f2bf(hi.x); tm[5]=f2bf(hi.y); tm[6]=f2bf(hi.z); tm[7]=f2bf(hi.w);
    am[ks] = __builtin_bit_cast(bf16x8, tm);
    const float4* xp = (const float4*)(x + (size_t)na*64 + kb);
    float4 xlo = xp[0], xhi = xp[1];
    us8 tx;
    tx[0]=f2bf(xlo.x); tx[1]=f2bf(xlo.y); tx[2]=f2bf(xlo.z); tx[3]=f2bf(xlo.w);
    tx[4]=f2bf(xhi.x); tx[5]=f2bf(xhi.y); tx[6]=f2bf(xhi.z); tx[7]=f2bf(xhi.w);
    ax[ks] = __builtin_bit_cast(bf16x8, tx);
  }

  floatx4 ai[12], ah[12];
#pragma unroll
  for (int nt = 0; nt < 12; ++nt){ ai[nt] = (floatx4)0.f; ah[nt] = (floatx4)0.f; }
#pragma unroll
  for (int nt = 0; nt < 12; ++nt){
    int r = nt*16 + col;   // output row of w (0..191)
#pragma unroll
    for (int ks = 0; ks < 2; ++ks){
      int kb = ks*32 + quad*8;
      bf16x8 bi = __builtin_bit_cast(bf16x8, *(const us8*)(wih + (size_t)r*64 + kb));
      ai[nt] = __builtin_amdgcn_mfma_f32_16x16x32_bf16(am[ks], bi, ai[nt], 0,0,0);
      bf16x8 bh = __builtin_bit_cast(bf16x8, *(const us8*)(whh + (size_t)r*64 + kb));
      ah[nt] = __builtin_amdgcn_mfma_f32_16x16x32_bf16(ax[ks], bh, ah[nt], 0,0,0);
    }
  }

#pragma unroll
  for (int nt = 0; nt < 4; ++nt){
    int d = nt*16 + col;
    float bir = b_ih[d],      bhr = b_hh[d];
    float biz = b_ih[64+d],   bhz = b_hh[64+d];
    float bin = b_ih[128+d],  bhn = b_hh[128+d];
#pragma unroll
    for (int rg = 0; rg < 4; ++rg){
      int node = wid*16 + quad*4 + rg;
      if (node >= N) continue;
      float rr = sigm(ai[nt  ][rg] + bir + ah[nt  ][rg] + bhr);
      float zz = sigm(ai[nt+4][rg] + biz + ah[nt+4][rg] + bhz);
      float nn = tanhf(ai[nt+8][rg] + bin + rr*(ah[nt+8][rg] + bhn));
      float xv = x[(size_t)node*64 + d];
      float hv = (1.f - zz)*nn + zz*xv;
      out[(size_t)node*64 + d] = fmaxf(hv, 0.f);
    }
  }
}

// MoE: gate logits + 4 experts via MFMA, softmax combine -> v[node][64] stores.
__global__ void __launch_bounds__(256) k_moe(
    const float* __restrict__ h,
    const unsigned short* __restrict__ gate_w, const float* __restrict__ gate_b,
    const unsigned short* __restrict__ exp_w,  const float* __restrict__ exp_b,
    float* __restrict__ v_out, int tiles, int N){
  __shared__ float gsm[4][16][4];
  int gwid = (int)(((long long)blockIdx.x*blockDim.x + threadIdx.x) >> 6);
  int w = threadIdx.x >> 6;
  int lane = threadIdx.x & 63;
  int col = lane & 15, quad = lane >> 4;
  bool active = gwid < tiles;

  floatx4 accg = (floatx4)0.f;
  floatx4 acce[4][4];
#pragma unroll
  for (int e=0;e<4;++e)
#pragma unroll
    for (int nt=0;nt<4;++nt) acce[e][nt] = (floatx4)0.f;

  if (active){
    int na = gwid*16 + col; if (na > N-1) na = N-1;
    bf16x8 a[2];
#pragma unroll
    for (int ks=0; ks<2; ++ks){
      int kb = ks*32 + quad*8;
      const float4* hp = (const float4*)(h + (size_t)na*64 + kb);
      float4 lo = hp[0], hi = hp[1];
      us8 th;
      th[0]=f2bf(lo.x); th[1]=f2bf(lo.y); th[2]=f2bf(lo.z); th[3]=f2bf(lo.w);
      th[4]=f2bf(hi.x); th[5]=f2bf(hi.y); th[6]=f2bf(hi.z); th[7]=f2bf(hi.w);
      a[ks] = __builtin_bit_cast(bf16x8, th);
      us8 braw = {0,0,0,0,0,0,0,0};
      if (col < 4) braw = *(const us8*)(gate_w + col*64 + kb);
      accg = __builtin_amdgcn_mfma_f32_16x16x32_bf16(a[ks], __builtin_bit_cast(bf16x8, braw), accg, 0,0,0);
    }
#pragma unroll
    for (int e=0;e<4;++e)
#pragma unroll
      for (int nt=0;nt<4;++nt)
#pragma unroll
        for (int ks=0;ks<2;++ks){
          int kb = ks*32 + quad*8;
          bf16x8 b = __builtin_bit_cast(bf16x8,
              *(const us8*)(exp_w + ((size_t)e*64 + nt*16 + col)*64 + kb));
          acce[e][nt] = __builtin_amdgcn_mfma_f32_16x16x32_bf16(a[ks], b, acce[e][nt], 0,0,0);
        }
    if (col < 4){
      float gb = gate_b[col];
#pragma unroll
      for (int rg=0;rg<4;++rg) gsm[w][quad*4+rg][col] = accg[rg] + gb;
    }
  }
  __syncthreads();
  if (!active) return;

#pragma unroll
  for (int rg=0; rg<4; ++rg){
    int nrow = quad*4 + rg;
    int node = gwid*16 + nrow;
    if (node >= N) continue;
    float g0=gsm[w][nrow][0], g1=gsm[w][nrow][1], g2=gsm[w][nrow][2], g3=gsm[w][nrow][3];
    float mx = fmaxf(fmaxf(g0,g1), fmaxf(g2,g3));
    float e0=__expf(g0-mx), e1=__expf(g1-mx), e2=__expf(g2-mx), e3=__expf(g3-mx);
    float inv = 1.f/(e0+e1+e2+e3);
    float w0=e0*inv, w1=e1*inv, w2=e2*inv, w3=e3*inv;
#pragma unroll
    for (int nt=0;nt<4;++nt){
      int o = nt*16 + col;
      float v = w0*fmaxf(acce[0][nt][rg] + exp_b[      o], 0.f)
              + w1*fmaxf(acce[1][nt][rg] + exp_b[ 64 + o], 0.f)
              + w2*fmaxf(acce[2][nt][rg] + exp_b[128 + o], 0.f)
              + w3*fmaxf(acce[3][nt][rg] + exp_b[192 + o], 0.f);
      v_out[(size_t)node*64 + o] = v;
    }
  }
}

__device__ __forceinline__ int lower_bound_i(const int* __restrict__ a, int n, int key){
  int lo = 0, hi = n;
  while (lo < hi){ int mid = (lo + hi) >> 1; if (a[mid] < key) lo = mid + 1; else hi = mid; }
  return lo;
}

// stage 1: B*PS blocks; block (g,s) reduces 1/PS of graph g's nodes.
__global__ void __launch_bounds__(256) k_pool(
    const float* __restrict__ v, const int* __restrict__ batch, int N,
    float* __restrict__ partial){
  __shared__ float red[4][64];
  int g = blockIdx.x / PS, s = blockIdx.x % PS;
  int t = threadIdx.x, d = t & 63, r = t >> 6;
  int start = lower_bound_i(batch, N, g);
  int end   = lower_bound_i(batch, N, g + 1);
  int len = end - start;
  int per = (len + PS - 1) / PS;
  int s0 = start + s*per;
  int s1 = s0 + per; if (s1 > end) s1 = end;
  float acc = 0.f;
  for (int i = s0 + r; i < s1; i += 4)
    acc += v[(size_t)i*64 + d];
  red[r][d] = acc;
  __syncthreads();
  if (r == 0)
    partial[(size_t)blockIdx.x*64 + d] = red[0][d] + red[1][d] + red[2][d] + red[3][d];
}

// stage 2: B blocks; sum PS partials, mean, write emb twice + logits head.
__global__ void __launch_bounds__(64) k_head(
    const float* __restrict__ partial, const int* __restrict__ batch, int N, int B,
    const float* __restrict__ ldxb,
    const float* __restrict__ proj_w, const float* __restrict__ proj_b,
    const float* __restrict__ fc_w, const float* __restrict__ fc_b,
    float* __restrict__ out){
  __shared__ float ges[64];
  int b = blockIdx.x, d = threadIdx.x;
  int start = lower_bound_i(batch, N, b);
  int end   = lower_bound_i(batch, N, b + 1);
  float sum = 0.f;
#pragma unroll
  for (int s = 0; s < PS; ++s)
    sum += partial[((size_t)b*PS + s)*64 + d];
  float ge = sum / fmaxf((float)(end - start), 1.f);
  ges[d] = ge;
  out[(size_t)b*64 + d]                = ge;
  out[(size_t)B*64 + (size_t)b*64 + d] = ge;
  __syncthreads();
  if (d < 10){
    float acc = fc_b[d];
    float fl = ldxb[b];
    const float* fr = fc_w + d*164;
    for (int p = 0; p < 100; ++p) acc += (fl*proj_w[p] + proj_b[p]) * fr[p];
    for (int dd = 0; dd < 64; ++dd) acc += ges[dd]*fr[100 + dd];
    out[(size_t)B*128 + (size_t)b*10 + d] = acc;
  }
}

extern "C" void kernel_launch(void* const* d_in, const int* in_sizes, int n_in,
                              void* d_out, int out_size, void* d_ws, size_t ws_size,
                              hipStream_t stream){
  const float* x      = (const float*)d_in[0];
  const int*   ei     = (const int*)d_in[1];
  const float* ea     = (const float*)d_in[2];
  const int*   batch  = (const int*)d_in[3];
  const float* ldxb   = (const float*)d_in[4];
  const float* w_edge1= (const float*)d_in[5];
  const float* b_edge1= (const float*)d_in[6];
  const float* w_ih1  = (const float*)d_in[7];
  const float* w_hh1  = (const float*)d_in[8];
  const float* b_ih1  = (const float*)d_in[9];
  const float* b_hh1  = (const float*)d_in[10];
  const float* w_edge2= (const float*)d_in[11];
  const float* b_edge2= (const float*)d_in[12];
  const float* w_ih2  = (const float*)d_in[13];
  const float* w_hh2  = (const float*)d_in[14];
  const float* b_ih2  = (const float*)d_in[15];
  const float* b_hh2  = (const float*)d_in[16];
  const float* gate_w = (const float*)d_in[17];
  const float* gate_b = (const float*)d_in[18];
  const float* exp_w  = (const float*)d_in[19];
  const float* exp_b  = (const float*)d_in[20];
  const float* proj_w = (const float*)d_in[21];
  const float* proj_b = (const float*)d_in[22];
  const float* fc_w   = (const float*)d_in[23];
  const float* fc_b   = (const float*)d_in[24];
  float* out = (float*)d_out;

  int N = in_sizes[0] / 64;
  int E = in_sizes[1] / 2;
  int B = in_sizes[4];
  int tiles = (N + 15) / 16;
  int nTot = N * 64;

  // workspace layout (all segment sizes multiples of 16B)
  float*   m       = (float*)d_ws;                      // N*64 f32 (also MoE v)
  float*   h       = m + (size_t)nTot;                  // N*64 f32
  int*     bkt_src = (int*)(h + (size_t)nTot);          // N*64 i32  [(sub*N+n)*8+k]
  ushort4* bkt_ea  = (ushort4*)(bkt_src + (size_t)nTot);// N*64 ushort4 (bf16x4)
  int*     cur     = (int*)(bkt_ea + (size_t)nTot);     // 8*N i32   [sub*N+n]
  int*     ovfcnt  = cur + (size_t)N*8;                 // 4 i32 (padded)
  int*     ovf     = ovfcnt + 4;                        // OVF_MAX i32
  unsigned short* wbf = (unsigned short*)(ovf + OVF_MAX); // 65792 bf16
  float*   partial = (float*)(wbf + 65792);             // B*PS*64 f32
  unsigned short* wih1bf = wbf;
  unsigned short* whh1bf = wbf + 12288;
  unsigned short* wih2bf = wbf + 24576;
  unsigned short* whh2bf = wbf + 36864;
  unsigned short* gatebf = wbf + 49152;
  unsigned short* expbf  = wbf + 49408;

  dim3 blk(256);
  int edgeBlocks = (E + 255)/256;
  int nodeWaveBlocks = (N + 3)/4;       // one wave per node
  int waveBlocks = (tiles + 3)/4;       // one wave per 16-node tile
  int N8 = N*8;
  int initBlocks = ((N8 > 65792 ? N8 : 65792) + 255)/256;

  k_init<<<initBlocks, blk, 0, stream>>>(w_ih1, w_hh1, w_ih2, w_hh2, gate_w, exp_w,
                                         wbf, cur, ovfcnt, N8);
  k_bucket<<<edgeBlocks, blk, 0, stream>>>(ei, ea, cur, bkt_src, bkt_ea, ovfcnt, ovf, E, N);
  // ---- layer 1 ----
  k_gather<<<nodeWaveBlocks, blk, 0, stream>>>(cur, bkt_src, bkt_ea, x, w_edge1, b_edge1, m, N);
  k_ovf<<<8, blk, 0, stream>>>(ei, ea, x, w_edge1, ovf, ovfcnt, m, E);
  k_gru<<<waveBlocks, blk, 0, stream>>>(m, x, wih1bf, whh1bf, b_ih1, b_hh1, h, tiles, N);
  // ---- layer 2 (in-place h update; wave/lane-exclusive, safe) ----
  k_gather<<<nodeWaveBlocks, blk, 0, stream>>>(cur, bkt_src, bkt_ea, h, w_edge2, b_edge2, m, N);
  k_ovf<<<8, blk, 0, stream>>>(ei, ea, h, w_edge2, ovf, ovfcnt, m, E);
  k_gru<<<waveBlocks, blk, 0, stream>>>(m, h, wih2bf, whh2bf, b_ih2, b_hh2, h, tiles, N);
  // ---- MoE -> v (reuse m), two-stage segmented-mean pool + heads ----
  k_moe<<<waveBlocks, blk, 0, stream>>>(h, gatebf, gate_b, expbf, exp_b, m, tiles, N);
  k_pool<<<B*PS, blk, 0, stream>>>(m, batch, N, partial);
  k_head<<<B, 64, 0, stream>>>(partial, batch, N, B, ldxb, proj_w, proj_b, fc_w, fc_b, out);
}